// Round 1
// baseline (268.777 us; speedup 1.0000x reference)
//
#include <hip/hip_runtime.h>
#include <math.h>

#define NROWS 2048
#define MCOLS 32

// K1: elementwise exp
__global__ __launch_bounds__(256) void k_exp(const float* __restrict__ expr,
                                             const float* __restrict__ tr,
                                             const float* __restrict__ risk,
                                             float* __restrict__ t,
                                             float* __restrict__ eH) {
    int i = blockIdx.x * 256 + threadIdx.x;
    if (i < NROWS * MCOLS) {
        t[i]  = __expf(expr[i] - tr[i]);
        eH[i] = __expf(risk[i]);
    }
}

// K2: per-column max -> scale[k] = 1/(max * 2*sigma*sqrt(2)); block 0 zeros out
__global__ __launch_bounds__(256) void k_colmax(const float* __restrict__ t,
                                                const float* __restrict__ sigma,
                                                float* __restrict__ scale,
                                                float* __restrict__ out) {
    int k = blockIdx.x;
    __shared__ float red[256];
    float m = -1e30f;
    for (int a = threadIdx.x; a < NROWS; a += 256)
        m = fmaxf(m, t[a * MCOLS + k]);
    red[threadIdx.x] = m;
    __syncthreads();
    for (int s = 128; s > 0; s >>= 1) {
        if (threadIdx.x < s)
            red[threadIdx.x] = fmaxf(red[threadIdx.x], red[threadIdx.x + s]);
        __syncthreads();
    }
    if (threadIdx.x == 0) {
        scale[k] = 1.0f / (red[0] * 2.0f * sigma[0] * sqrtf(2.0f));
        if (k == 0) out[0] = 0.0f;   // stream-ordered before k_main's atomics
    }
}

// K3: main O(N^2 * M) loop. grid = (MCOLS, NROWS/256), block = 256.
__global__ __launch_bounds__(256) void k_main(const float* __restrict__ t,
                                              const float* __restrict__ eH,
                                              const float* __restrict__ scale,
                                              const float* __restrict__ risk,
                                              const float* __restrict__ event,
                                              float* __restrict__ out) {
    int k  = blockIdx.x;
    int j0 = blockIdx.y * 256;

    __shared__ float s_ti[NROWS];
    __shared__ float s_eH[NROWS];
    __shared__ float warpsum[4];

    float sc = scale[k];
    for (int a = threadIdx.x; a < NROWS; a += 256) {
        s_ti[a] = t[a * MCOLS + k] * sc;
        s_eH[a] = eH[a * MCOLS + k];
    }
    __syncthreads();

    int j = j0 + threadIdx.x;
    float tj = s_ti[j];

    // cumsum[j,k] = sum_a eH[a] * (0.5 + 0.5*erf(ti[a]-ti[j])) + 0.5*eH[j]
    float acc0 = 0.f, acc1 = 0.f, acc2 = 0.f, acc3 = 0.f;
    for (int a = 0; a < NROWS; a += 4) {
        acc0 += s_eH[a + 0] * (0.5f + 0.5f * erff(s_ti[a + 0] - tj));
        acc1 += s_eH[a + 1] * (0.5f + 0.5f * erff(s_ti[a + 1] - tj));
        acc2 += s_eH[a + 2] * (0.5f + 0.5f * erff(s_ti[a + 2] - tj));
        acc3 += s_eH[a + 3] * (0.5f + 0.5f * erff(s_ti[a + 3] - tj));
    }
    float acc = ((acc0 + acc1) + (acc2 + acc3)) + 0.5f * s_eH[j];

    // negated loglik contribution: (log(cumsum) - risk) * event
    float c = (logf(acc) - risk[j * MCOLS + k]) * event[j * MCOLS + k];

    // block reduction: wave shuffle then LDS across 4 waves
    for (int off = 32; off > 0; off >>= 1)
        c += __shfl_down(c, off, 64);
    if ((threadIdx.x & 63) == 0) warpsum[threadIdx.x >> 6] = c;
    __syncthreads();
    if (threadIdx.x == 0) {
        float s = (warpsum[0] + warpsum[1]) + (warpsum[2] + warpsum[3]);
        atomicAdd(out, s);
    }
}

extern "C" void kernel_launch(void* const* d_in, const int* in_sizes, int n_in,
                              void* d_out, int out_size, void* d_ws, size_t ws_size,
                              hipStream_t stream) {
    const float* risk  = (const float*)d_in[0];
    const float* expr  = (const float*)d_in[1];
    const float* tr    = (const float*)d_in[2];
    const float* event = (const float*)d_in[3];
    const float* sigma = (const float*)d_in[4];
    float* out = (float*)d_out;

    float* ws_t     = (float*)d_ws;                 // N*M
    float* ws_eH    = ws_t + NROWS * MCOLS;         // N*M
    float* ws_scale = ws_eH + NROWS * MCOLS;        // M

    k_exp<<<(NROWS * MCOLS + 255) / 256, 256, 0, stream>>>(expr, tr, risk, ws_t, ws_eH);
    k_colmax<<<MCOLS, 256, 0, stream>>>(ws_t, sigma, ws_scale, out);
    k_main<<<dim3(MCOLS, NROWS / 256), 256, 0, stream>>>(ws_t, ws_eH, ws_scale,
                                                         risk, event, out);
}

// Round 2
// 94.912 us; speedup vs baseline: 2.8318x; 2.8318x over previous
//
#include <hip/hip_runtime.h>
#include <math.h>

#define NROWS 2048
#define MCOLS 32
#define P_SPLIT 8
#define CHUNK (NROWS / P_SPLIT)   // 256

// K1 (prep): one block per column k.
// Computes t=exp(expr-tr), eH=exp(risk), column max of t, column sum of eH.
// Writes interleaved (ti*scale, eH) float2 column-major, and initializes
// cumsum[k*N+j] = 0.5*(S + eH[j])  (constant phi half-sum + diagonal term).
__global__ __launch_bounds__(256) void k_prep(const float* __restrict__ expr,
                                              const float* __restrict__ tr,
                                              const float* __restrict__ risk,
                                              const float* __restrict__ sigma,
                                              float2* __restrict__ te,
                                              float* __restrict__ cumsum,
                                              float* __restrict__ out) {
    int k = blockIdx.x, tid = threadIdx.x;
    __shared__ float l_t[NROWS];
    __shared__ float l_e[NROWS];
    __shared__ float red[256];

    float mx = -1e30f, sm = 0.0f;
#pragma unroll
    for (int i = 0; i < NROWS / 256; i++) {
        int a = tid + i * 256;
        int idx = a * MCOLS + k;
        float tv = __expf(expr[idx] - tr[idx]);
        float ev = __expf(risk[idx]);
        l_t[a] = tv; l_e[a] = ev;
        mx = fmaxf(mx, tv);
        sm += ev;
    }
    // block max
    red[tid] = mx; __syncthreads();
    for (int s = 128; s > 0; s >>= 1) {
        if (tid < s) red[tid] = fmaxf(red[tid], red[tid + s]);
        __syncthreads();
    }
    float m = red[0];
    __syncthreads();
    // block sum
    red[tid] = sm; __syncthreads();
    for (int s = 128; s > 0; s >>= 1) {
        if (tid < s) red[tid] += red[tid + s];
        __syncthreads();
    }
    float S = red[0];

    float scale = 1.0f / (m * 2.0f * sigma[0] * sqrtf(2.0f));
#pragma unroll
    for (int i = 0; i < NROWS / 256; i++) {
        int a = tid + i * 256;
        te[k * NROWS + a] = make_float2(l_t[a] * scale, l_e[a]);
        cumsum[k * NROWS + a] = 0.5f * (S + l_e[a]);
    }
    if (k == 0 && tid == 0) out[0] = 0.0f;
}

// K2 (partial): grid (MCOLS, NROWS/256, P_SPLIT), block 256.
// Each thread owns one j; each block covers a CHUNK of a.
// acc = sum_a eH[a] * erf(ti[a]-ti[j]); |x|<=0.3536 so odd Taylor poly:
// erf(x) = x*(c1 + c3 x^2 + c5 x^4 + c7 x^6), trunc err < 5e-7.
__global__ __launch_bounds__(256) void k_partial(const float2* __restrict__ te,
                                                 float* __restrict__ cumsum) {
    const float c1 = 1.1283791671f;     //  2/sqrt(pi)
    const float c3 = -0.3761263890f;    // -2/(3 sqrt(pi))
    const float c5 = 0.1128379167f;     //  2/(10 sqrt(pi))
    const float c7 = -0.0268661706f;    // -2/(42 sqrt(pi))

    int k  = blockIdx.x;
    int j  = blockIdx.y * 256 + threadIdx.x;
    int a0 = blockIdx.z * CHUNK;

    __shared__ float2 s_te[CHUNK];
    s_te[threadIdx.x] = te[k * NROWS + a0 + threadIdx.x];
    float tj = te[k * NROWS + j].x;
    __syncthreads();

    float acc0 = 0.f, acc1 = 0.f, acc2 = 0.f, acc3 = 0.f;
#pragma unroll 4
    for (int a = 0; a < CHUNK; a += 4) {
        {
            float2 v = s_te[a + 0];
            float x = v.x - tj, x2 = x * x;
            float p = fmaf(fmaf(fmaf(c7, x2, c5), x2, c3), x2, c1);
            acc0 = fmaf(x * v.y, p, acc0);
        }
        {
            float2 v = s_te[a + 1];
            float x = v.x - tj, x2 = x * x;
            float p = fmaf(fmaf(fmaf(c7, x2, c5), x2, c3), x2, c1);
            acc1 = fmaf(x * v.y, p, acc1);
        }
        {
            float2 v = s_te[a + 2];
            float x = v.x - tj, x2 = x * x;
            float p = fmaf(fmaf(fmaf(c7, x2, c5), x2, c3), x2, c1);
            acc2 = fmaf(x * v.y, p, acc2);
        }
        {
            float2 v = s_te[a + 3];
            float x = v.x - tj, x2 = x * x;
            float p = fmaf(fmaf(fmaf(c7, x2, c5), x2, c3), x2, c1);
            acc3 = fmaf(x * v.y, p, acc3);
        }
    }
    float acc = ((acc0 + acc1) + (acc2 + acc3));
    atomicAdd(&cumsum[k * NROWS + j], 0.5f * acc);
}

// K3 (loss): c = (log(cumsum) - risk) * event, global reduce.
__global__ __launch_bounds__(256) void k_loss(const float* __restrict__ cumsum,
                                              const float* __restrict__ risk,
                                              const float* __restrict__ event,
                                              float* __restrict__ out) {
    int i = blockIdx.x * 256 + threadIdx.x;   // i = k*NROWS + j
    int k = i >> 11;
    int j = i & (NROWS - 1);
    float c = (__logf(cumsum[i]) - risk[j * MCOLS + k]) * event[j * MCOLS + k];

    __shared__ float warpsum[4];
    for (int off = 32; off > 0; off >>= 1)
        c += __shfl_down(c, off, 64);
    if ((threadIdx.x & 63) == 0) warpsum[threadIdx.x >> 6] = c;
    __syncthreads();
    if (threadIdx.x == 0) {
        float s = (warpsum[0] + warpsum[1]) + (warpsum[2] + warpsum[3]);
        atomicAdd(out, s);
    }
}

extern "C" void kernel_launch(void* const* d_in, const int* in_sizes, int n_in,
                              void* d_out, int out_size, void* d_ws, size_t ws_size,
                              hipStream_t stream) {
    const float* risk  = (const float*)d_in[0];
    const float* expr  = (const float*)d_in[1];
    const float* tr    = (const float*)d_in[2];
    const float* event = (const float*)d_in[3];
    const float* sigma = (const float*)d_in[4];
    float* out = (float*)d_out;

    float2* ws_te     = (float2*)d_ws;                    // N*M float2 (512 KB)
    float*  ws_cumsum = (float*)(ws_te + NROWS * MCOLS);  // N*M float  (256 KB)

    k_prep<<<MCOLS, 256, 0, stream>>>(expr, tr, risk, sigma, ws_te, ws_cumsum, out);
    k_partial<<<dim3(MCOLS, NROWS / 256, P_SPLIT), 256, 0, stream>>>(ws_te, ws_cumsum);
    k_loss<<<(NROWS * MCOLS) / 256, 256, 0, stream>>>(ws_cumsum, risk, event, out);
}

// Round 3
// 93.662 us; speedup vs baseline: 2.8697x; 1.0134x over previous
//
#include <hip/hip_runtime.h>
#include <math.h>

#define NROWS 2048
#define MCOLS 32
#define P_SPLIT 8
#define CHUNK (NROWS / P_SPLIT)   // 256

// K_init: zero the 32 max-bits, 32 column sums, and the output scalar.
__global__ __launch_bounds__(128) void k_init(unsigned int* __restrict__ maxbits,
                                              float* __restrict__ sumS,
                                              float* __restrict__ out) {
    int t = threadIdx.x;
    if (t < MCOLS) { maxbits[t] = 0u; sumS[t] = 0.0f; }
    if (t == 0) out[0] = 0.0f;
}

// K0: fully-coalesced elementwise pass. i = a*MCOLS + k (row-major).
// Writes transposed (t, eH) float2 at te[k*NROWS + a], zeroes cumsum,
// reduces per-block (8 rows x 32 cols) then atomics for column max/sum.
__global__ __launch_bounds__(256) void k_elem(const float* __restrict__ expr,
                                              const float* __restrict__ tr,
                                              const float* __restrict__ risk,
                                              float2* __restrict__ te,
                                              float* __restrict__ cumsum,
                                              unsigned int* __restrict__ maxbits,
                                              float* __restrict__ sumS) {
    int tid = threadIdx.x;
    int i = blockIdx.x * 256 + tid;          // 0 .. N*M-1
    int a = i >> 5;                          // row
    int k = i & (MCOLS - 1);                 // col

    float tv = __expf(expr[i] - tr[i]);
    float ev = __expf(risk[i]);
    te[k * NROWS + a] = make_float2(tv, ev);
    cumsum[i] = 0.0f;

    __shared__ float smax[256];
    __shared__ float ssum[256];
    smax[tid] = tv; ssum[tid] = ev;
    __syncthreads();
    if (tid < MCOLS) {                       // tid == column
        float m = smax[tid], s = ssum[tid];
#pragma unroll
        for (int r = 1; r < 8; r++) {
            m = fmaxf(m, smax[tid + 32 * r]);  // distinct banks per lane
            s += ssum[tid + 32 * r];
        }
        atomicMax(&maxbits[tid], __float_as_uint(m));  // t>0: uint order == float order
        atomicAdd(&sumS[tid], s);
    }
}

// K2: main O(N^2*M) partial sums. grid (MCOLS, NROWS/256, P_SPLIT), block 256.
// acc = sum_a eH[a] * erf(ti[a]-ti[j]); |x| <= 1/(2*sqrt(2)) so odd Taylor:
// erf(x) = x*(c1 + c3 x^2 + c5 x^4 + c7 x^6), trunc err < 5e-7.
__global__ __launch_bounds__(256) void k_partial(const float2* __restrict__ te,
                                                 const unsigned int* __restrict__ maxbits,
                                                 const float* __restrict__ sigma,
                                                 float* __restrict__ cumsum) {
    const float c1 = 1.1283791671f;
    const float c3 = -0.3761263890f;
    const float c5 = 0.1128379167f;
    const float c7 = -0.0268661706f;

    int k  = blockIdx.x;
    int j  = blockIdx.y * 256 + threadIdx.x;
    int a0 = blockIdx.z * CHUNK;

    float sc = 1.0f / (__uint_as_float(maxbits[k]) * 2.0f * sigma[0] * sqrtf(2.0f));

    __shared__ float2 s_te[CHUNK];
    float2 mine = te[k * NROWS + a0 + threadIdx.x];
    s_te[threadIdx.x] = make_float2(mine.x * sc, mine.y);
    float tj = te[k * NROWS + j].x * sc;
    __syncthreads();

    float acc0 = 0.f, acc1 = 0.f, acc2 = 0.f, acc3 = 0.f;
#pragma unroll 4
    for (int a = 0; a < CHUNK; a += 4) {
        {
            float2 v = s_te[a + 0];
            float x = v.x - tj, x2 = x * x;
            float p = fmaf(fmaf(fmaf(c7, x2, c5), x2, c3), x2, c1);
            acc0 = fmaf(x * v.y, p, acc0);
        }
        {
            float2 v = s_te[a + 1];
            float x = v.x - tj, x2 = x * x;
            float p = fmaf(fmaf(fmaf(c7, x2, c5), x2, c3), x2, c1);
            acc1 = fmaf(x * v.y, p, acc1);
        }
        {
            float2 v = s_te[a + 2];
            float x = v.x - tj, x2 = x * x;
            float p = fmaf(fmaf(fmaf(c7, x2, c5), x2, c3), x2, c1);
            acc2 = fmaf(x * v.y, p, acc2);
        }
        {
            float2 v = s_te[a + 3];
            float x = v.x - tj, x2 = x * x;
            float p = fmaf(fmaf(fmaf(c7, x2, c5), x2, c3), x2, c1);
            acc3 = fmaf(x * v.y, p, acc3);
        }
    }
    float acc = ((acc0 + acc1) + (acc2 + acc3));
    atomicAdd(&cumsum[k * NROWS + j], 0.5f * acc);
}

// K3: cum = partial + 0.5*(S_k + eH[j,k]); c = (log(cum) - risk)*event; reduce.
__global__ __launch_bounds__(256) void k_loss(const float* __restrict__ cumsum,
                                              const float2* __restrict__ te,
                                              const float* __restrict__ sumS,
                                              const float* __restrict__ risk,
                                              const float* __restrict__ event,
                                              float* __restrict__ out) {
    int i = blockIdx.x * 256 + threadIdx.x;  // i = k*NROWS + j
    int k = i >> 11;
    int j = i & (NROWS - 1);
    float cum = cumsum[i] + 0.5f * (sumS[k] + te[i].y);
    float c = (__logf(cum) - risk[j * MCOLS + k]) * event[j * MCOLS + k];

    __shared__ float warpsum[4];
    for (int off = 32; off > 0; off >>= 1)
        c += __shfl_down(c, off, 64);
    if ((threadIdx.x & 63) == 0) warpsum[threadIdx.x >> 6] = c;
    __syncthreads();
    if (threadIdx.x == 0) {
        float s = (warpsum[0] + warpsum[1]) + (warpsum[2] + warpsum[3]);
        atomicAdd(out, s);
    }
}

extern "C" void kernel_launch(void* const* d_in, const int* in_sizes, int n_in,
                              void* d_out, int out_size, void* d_ws, size_t ws_size,
                              hipStream_t stream) {
    const float* risk  = (const float*)d_in[0];
    const float* expr  = (const float*)d_in[1];
    const float* tr    = (const float*)d_in[2];
    const float* event = (const float*)d_in[3];
    const float* sigma = (const float*)d_in[4];
    float* out = (float*)d_out;

    float2*       ws_te     = (float2*)d_ws;                    // N*M float2
    float*        ws_cumsum = (float*)(ws_te + NROWS * MCOLS);  // N*M float
    unsigned int* ws_max    = (unsigned int*)(ws_cumsum + NROWS * MCOLS); // M
    float*        ws_sumS   = (float*)(ws_max + MCOLS);         // M

    k_init<<<1, 128, 0, stream>>>(ws_max, ws_sumS, out);
    k_elem<<<(NROWS * MCOLS) / 256, 256, 0, stream>>>(expr, tr, risk, ws_te,
                                                      ws_cumsum, ws_max, ws_sumS);
    k_partial<<<dim3(MCOLS, NROWS / 256, P_SPLIT), 256, 0, stream>>>(ws_te, ws_max,
                                                                     sigma, ws_cumsum);
    k_loss<<<(NROWS * MCOLS) / 256, 256, 0, stream>>>(ws_cumsum, ws_te, ws_sumS,
                                                      risk, event, out);
}

// Round 4
// 76.248 us; speedup vs baseline: 3.5250x; 1.2284x over previous
//
#include <hip/hip_runtime.h>
#include <math.h>

#define NROWS 2048
#define MCOLS 32

// Taylor erf on |x| <= 1/(2*sqrt(2)): erf(x) = c1 x + c3 x^3 + c5 x^5 + c7 x^7
#define C1 1.1283791671f
#define C3 (-0.3761263890f)
#define C5 0.1128379167f
#define C7 (-0.0268661706f)

// K0: zero moment accumulators, max bits, output scalar.
__global__ __launch_bounds__(256) void k_init(float* __restrict__ Mp,
                                              unsigned int* __restrict__ maxbits,
                                              float* __restrict__ out) {
    int t = threadIdx.x;
    Mp[t] = 0.0f;                       // 8 x 32 moments, layout [q*32 + k]
    if (t < MCOLS) maxbits[t] = 0u;
    if (t == 0) out[0] = 0.0f;
}

// K1: coalesced elementwise. t=exp(expr-tr), e=exp(risk) -> ws (row-major).
// Per-block (8 rows x 32 cols): column max -> atomicMax, unscaled moments
// M'_q[k] = sum_a e*t^q (q=0..7) -> atomicAdd. Thread (q,k) = (tid>>5, tid&31).
__global__ __launch_bounds__(256) void k_elem(const float* __restrict__ expr,
                                              const float* __restrict__ tr,
                                              const float* __restrict__ risk,
                                              float* __restrict__ ws_t,
                                              float* __restrict__ ws_e,
                                              float* __restrict__ Mp,
                                              unsigned int* __restrict__ maxbits) {
    int tid = threadIdx.x;
    int i = blockIdx.x * 256 + tid;     // i = a*32 + k, row-major
    float tv = __expf(expr[i] - tr[i]);
    float ev = __expf(risk[i]);
    ws_t[i] = tv;
    ws_e[i] = ev;

    __shared__ float sm_t[256];
    __shared__ float sm_e[256];
    sm_t[tid] = tv; sm_e[tid] = ev;
    __syncthreads();

    int k = tid & 31;
    int q = tid >> 5;                   // 0..7
    float partial = 0.0f, mx = 0.0f;
#pragma unroll
    for (int r = 0; r < 8; r++) {
        float t = sm_t[r * 32 + k];
        float e = sm_e[r * 32 + k];
        float p = e;
        for (int m = 0; m < q; m++) p *= t;   // e * t^q
        partial += p;
        mx = fmaxf(mx, t);
    }
    atomicAdd(&Mp[q * 32 + k], partial);
    if (q == 0) atomicMax(&maxbits[k], __float_as_uint(mx));  // t>0: uint order ok
}

// K2: one tiny block. Per column: scale s, scaled moments M_q = M'_q s^q,
// binomial-combined Horner coefficients D_0..7, plus s and 0.5*S.
__global__ __launch_bounds__(64) void k_coeff(const float* __restrict__ Mp,
                                              const unsigned int* __restrict__ maxbits,
                                              const float* __restrict__ sigma,
                                              float* __restrict__ D,       // [q*32+k]
                                              float* __restrict__ scaleS,  // [k]
                                              float* __restrict__ Shalf) { // [k]
    int k = threadIdx.x;
    if (k >= MCOLS) return;
    float s = 1.0f / (__uint_as_float(maxbits[k]) * 2.0f * sigma[0] * sqrtf(2.0f));
    float M[8];
    float sp = 1.0f;
#pragma unroll
    for (int q = 0; q < 8; q++) { M[q] = Mp[q * 32 + k] * sp; sp *= s; }
    D[0 * 32 + k] = C1 * M[1] +         C3 * M[3] +         C5 * M[5] +        C7 * M[7];
    D[1 * 32 + k] = C1 * M[0] + 3.0f *  C3 * M[2] + 5.0f *  C5 * M[4] + 7.0f * C7 * M[6];
    D[2 * 32 + k] = 3.0f * C3 * M[1] + 10.0f * C5 * M[3] + 21.0f * C7 * M[5];
    D[3 * 32 + k] = C3 * M[0] + 10.0f * C5 * M[2] + 35.0f * C7 * M[4];
    D[4 * 32 + k] = 5.0f * C5 * M[1] + 35.0f * C7 * M[3];
    D[5 * 32 + k] = C5 * M[0] + 21.0f * C7 * M[2];
    D[6 * 32 + k] = 7.0f * C7 * M[1];
    D[7 * 32 + k] = C7 * M[0];
    scaleS[k] = s;
    Shalf[k]  = 0.5f * M[0];            // 0.5 * sum_a e_a
}

// K3: per element (j,k): z = t*s; acc = sum_i (-z)^i D_i (Horner);
// cum = 0.5*S + 0.5*(acc + e_j); c = (log(cum)-risk)*event; reduce -> out.
__global__ __launch_bounds__(256) void k_final(const float* __restrict__ ws_t,
                                               const float* __restrict__ ws_e,
                                               const float* __restrict__ D,
                                               const float* __restrict__ scaleS,
                                               const float* __restrict__ Shalf,
                                               const float* __restrict__ risk,
                                               const float* __restrict__ event,
                                               float* __restrict__ out) {
    int tid = threadIdx.x;
    int i = blockIdx.x * 256 + tid;     // i = j*32 + k
    __shared__ float sD[256];
    __shared__ float sSc[32];
    __shared__ float sSh[32];
    __shared__ float warpsum[4];
    sD[tid] = D[tid];
    if (tid < 32) { sSc[tid] = scaleS[tid]; sSh[tid] = Shalf[tid]; }
    __syncthreads();

    int k = i & 31;
    float w = -(ws_t[i] * sSc[k]);
    float acc = sD[7 * 32 + k];
#pragma unroll
    for (int q = 6; q >= 0; q--)
        acc = fmaf(acc, w, sD[q * 32 + k]);
    float cum = sSh[k] + 0.5f * (acc + ws_e[i]);
    float c = (__logf(cum) - risk[i]) * event[i];

    for (int off = 32; off > 0; off >>= 1)
        c += __shfl_down(c, off, 64);
    if ((tid & 63) == 0) warpsum[tid >> 6] = c;
    __syncthreads();
    if (tid == 0) {
        float s = (warpsum[0] + warpsum[1]) + (warpsum[2] + warpsum[3]);
        atomicAdd(out, s);
    }
}

extern "C" void kernel_launch(void* const* d_in, const int* in_sizes, int n_in,
                              void* d_out, int out_size, void* d_ws, size_t ws_size,
                              hipStream_t stream) {
    const float* risk  = (const float*)d_in[0];
    const float* expr  = (const float*)d_in[1];
    const float* tr    = (const float*)d_in[2];
    const float* event = (const float*)d_in[3];
    const float* sigma = (const float*)d_in[4];
    float* out = (float*)d_out;

    float*        ws_t    = (float*)d_ws;                    // N*M
    float*        ws_e    = ws_t + NROWS * MCOLS;            // N*M
    float*        ws_Mp   = ws_e + NROWS * MCOLS;            // 8*32
    float*        ws_D    = ws_Mp + 8 * MCOLS;               // 8*32
    float*        ws_sc   = ws_D + 8 * MCOLS;                // 32
    float*        ws_Sh   = ws_sc + MCOLS;                   // 32
    unsigned int* ws_max  = (unsigned int*)(ws_Sh + MCOLS);  // 32

    k_init<<<1, 256, 0, stream>>>(ws_Mp, ws_max, out);
    k_elem<<<(NROWS * MCOLS) / 256, 256, 0, stream>>>(expr, tr, risk, ws_t, ws_e,
                                                      ws_Mp, ws_max);
    k_coeff<<<1, 64, 0, stream>>>(ws_Mp, ws_max, sigma, ws_D, ws_sc, ws_Sh);
    k_final<<<(NROWS * MCOLS) / 256, 256, 0, stream>>>(ws_t, ws_e, ws_D, ws_sc,
                                                       ws_Sh, risk, event, out);
}